// Round 1
// baseline (450.796 us; speedup 1.0000x reference)
//
#include <hip/hip_runtime.h>
#include <stdint.h>

#define DIM 768
#define NH 12
#define HD 64
#define BSZ 4
#define SEQ 2048
#define MROWS (BSZ*SEQ)   // 8192

typedef __attribute__((ext_vector_type(8))) short v8s;   // 8 bf16 (4 VGPRs)
typedef __attribute__((ext_vector_type(4))) float v4f;   // 4 fp32 acc

__device__ __forceinline__ uint16_t f2bf(float x) {
  union { float f; uint32_t u; } v; v.f = x;
  uint32_t r = v.u + 0x7fffu + ((v.u >> 16) & 1u);   // RNE
  return (uint16_t)(r >> 16);
}

// ---------------- pre-pass: fp32 -> bf16 (vectorized) ----------------
__global__ void cvt_bf16_kernel(const float* __restrict__ src,
                                uint16_t* __restrict__ dst, int n4) {
  int i = blockIdx.x * blockDim.x + threadIdx.x;
  if (i >= n4) return;
  float4 v = ((const float4*)src)[i];
  ushort4 o;
  o.x = f2bf(v.x); o.y = f2bf(v.y); o.z = f2bf(v.z); o.w = f2bf(v.w);
  ((ushort4*)dst)[i] = o;
}

// ---------------- pre-pass: mask int32 -> u8 (4x less L2/L3 traffic) ----------------
__global__ void mask_cvt_kernel(const int* __restrict__ src,
                                unsigned char* __restrict__ dst, int n4) {
  int i = blockIdx.x * blockDim.x + threadIdx.x;
  if (i >= n4) return;
  int4 v = ((const int4*)src)[i];
  uchar4 o;
  o.x = (unsigned char)v.x; o.y = (unsigned char)v.y;
  o.z = (unsigned char)v.z; o.w = (unsigned char)v.w;
  ((uchar4*)dst)[i] = o;
}

// ---------------- pre-pass: W [K][N] fp32 -> WT [N][K] bf16 ----------------
__global__ void wtrans_kernel(const float* __restrict__ Wq, const float* __restrict__ Wk,
                              const float* __restrict__ Wv, const float* __restrict__ Wo,
                              uint16_t* __restrict__ WT) {
  __shared__ float tile[32][33];
  int z = blockIdx.z;
  const float* src = (z==0) ? Wq : (z==1) ? Wk : (z==2) ? Wv : Wo;
  uint16_t* dst = WT + (size_t)z * DIM * DIM;
  int tx = threadIdx.x, ty = threadIdx.y;
  int x  = blockIdx.x * 32 + tx;      // n (col of src)
  int y0 = blockIdx.y * 32;           // k base
  for (int j = ty; j < 32; j += 8)
    tile[j][tx] = src[(size_t)(y0 + j) * DIM + x];
  __syncthreads();
  int xo = y0 + tx;                   // k (col of dst)
  for (int j = ty; j < 32; j += 8)
    dst[(size_t)(blockIdx.x * 32 + j) * DIM + xo] = f2bf(tile[tx][j]);
}

// ---------------- GEMM: C[M=8192,N=768] = A(bf16) @ WT^T + bias ----------------
// mode 0: Q  -> Qw [b,h,s,d] * SCALE     mode 1: K -> Kw [b,h,s,d]
// mode 2: V  -> Vw [b,h,d,s] (transposed) mode 3: O -> d_out fp32 [m,n]
__global__ __launch_bounds__(256) void gemm_kernel(
    const uint16_t* __restrict__ Xf, const uint16_t* __restrict__ Xt,
    const uint16_t* __restrict__ WT, const uint16_t* __restrict__ AO,
    const float* __restrict__ bq, const float* __restrict__ bk,
    const float* __restrict__ bv, const float* __restrict__ bo,
    uint16_t* __restrict__ Qw, uint16_t* __restrict__ Kw, uint16_t* __restrict__ Vw,
    float* __restrict__ Out, int mode_base)
{
  // stride 56 elems = 112 B = 28 banks: frag reads land 2 lanes/bank (free), 16B aligned
  __shared__ alignas(16) uint16_t As[128 * 56];
  __shared__ alignas(16) uint16_t Bs[128 * 56];
  int mode = mode_base + blockIdx.z;
  const uint16_t* A = (mode == 0) ? Xf : (mode == 3 ? AO : Xt);
  const uint16_t* W = WT + (size_t)mode * DIM * DIM;
  const float* bias = (mode == 0) ? bq : (mode == 1) ? bk : (mode == 2) ? bv : bo;

  int m0 = blockIdx.x * 128, n0 = blockIdx.y * 128;
  int tid = threadIdx.x;
  int wave = tid >> 6, lane = tid & 63, lr = lane & 15, quad = lane >> 4;
  int wm = (wave >> 1) * 64, wn = (wave & 1) * 64;

  v4f acc[4][4];
  v4f vz = {0.f, 0.f, 0.f, 0.f};
  #pragma unroll
  for (int i = 0; i < 4; i++)
    #pragma unroll
    for (int j = 0; j < 4; j++) acc[i][j] = vz;

  for (int k0 = 0; k0 < DIM; k0 += 32) {
    #pragma unroll
    for (int c = tid; c < 512; c += 256) {
      int row = c >> 2, seg = c & 3;
      *(uint4*)&As[row * 56 + seg * 8] =
          *(const uint4*)&A[(size_t)(m0 + row) * DIM + k0 + seg * 8];
      *(uint4*)&Bs[row * 56 + seg * 8] =
          *(const uint4*)&W[(size_t)(n0 + row) * DIM + k0 + seg * 8];
    }
    __syncthreads();
    v8s af[4], bfr[4];
    #pragma unroll
    for (int i = 0; i < 4; i++)
      af[i] = *(const v8s*)&As[(wm + i * 16 + lr) * 56 + quad * 8];
    #pragma unroll
    for (int j = 0; j < 4; j++)
      bfr[j] = *(const v8s*)&Bs[(wn + j * 16 + lr) * 56 + quad * 8];
    #pragma unroll
    for (int i = 0; i < 4; i++)
      #pragma unroll
      for (int j = 0; j < 4; j++)
        acc[i][j] = __builtin_amdgcn_mfma_f32_16x16x32_bf16(af[i], bfr[j], acc[i][j], 0, 0, 0);
    __syncthreads();
  }

  float bj[4];
  #pragma unroll
  for (int j = 0; j < 4; j++) bj[j] = bias[n0 + wn + j * 16 + lr];

  if (mode == 3) {
    #pragma unroll
    for (int i = 0; i < 4; i++) {
      int m = m0 + wm + i * 16 + quad * 4;
      #pragma unroll
      for (int j = 0; j < 4; j++) {
        int n = n0 + wn + j * 16 + lr;
        #pragma unroll
        for (int r = 0; r < 4; r++)
          Out[(size_t)(m + r) * DIM + n] = acc[i][j][r] + bj[j];
      }
    }
  } else if (mode == 2) {
    #pragma unroll
    for (int i = 0; i < 4; i++) {
      int m = m0 + wm + i * 16 + quad * 4;
      int b = m >> 11, s = m & 2047;
      #pragma unroll
      for (int j = 0; j < 4; j++) {
        int n = n0 + wn + j * 16 + lr;
        int h = n >> 6, d = n & 63;
        ushort4 pk;
        pk.x = f2bf(acc[i][j][0] + bj[j]);
        pk.y = f2bf(acc[i][j][1] + bj[j]);
        pk.z = f2bf(acc[i][j][2] + bj[j]);
        pk.w = f2bf(acc[i][j][3] + bj[j]);
        *(ushort4*)&Vw[(size_t)((b * NH + h) * HD + d) * SEQ + s] = pk;  // s 4-aligned
      }
    }
  } else {
    uint16_t* Dst = (mode == 0) ? Qw : Kw;
    float scale = (mode == 0) ? 0.125f : 1.0f;   // HEAD_DIM^-0.5
    #pragma unroll
    for (int i = 0; i < 4; i++) {
      int m = m0 + wm + i * 16 + quad * 4;
      int b = m >> 11, s0 = m & 2047;
      #pragma unroll
      for (int j = 0; j < 4; j++) {
        int n = n0 + wn + j * 16 + lr;
        int h = n >> 6, d = n & 63;
        #pragma unroll
        for (int r = 0; r < 4; r++) {
          float v = (acc[i][j][r] + bj[j]) * scale;
          Dst[(size_t)((b * NH + h) * SEQ + (s0 + r)) * HD + d] = f2bf(v);
        }
      }
    }
  }
}

// ---------------- flash attention (online softmax, 64 Q-rows/block) ----------------
__global__ __launch_bounds__(256) void flash_kernel(
    const uint16_t* __restrict__ Qg, const uint16_t* __restrict__ Kg,
    const uint16_t* __restrict__ Vg, const unsigned char* __restrict__ Mg,
    uint16_t* __restrict__ AO)
{
  // stride 72 elems = 144 B = 36 banks (= 4 mod 32): b128 frag reads phase optimally
  __shared__ alignas(16) uint16_t Ks[64 * 72];
  __shared__ alignas(16) uint16_t Vs[64 * 72];       // V^T: [d][kk]
  __shared__ alignas(16) uint16_t Ps[4 * 16 * 72];   // per-wave P round-trip

  int tid = threadIdx.x, wave = tid >> 6, lane = tid & 63, lr = lane & 15, quad = lane >> 4;
  int bh = blockIdx.y;
  int b = bh / NH, h = bh - b * NH;
  int q0 = blockIdx.x * 64;
  const uint16_t* Qp = Qg + (size_t)bh * SEQ * HD;
  const uint16_t* Kp = Kg + (size_t)bh * SEQ * HD;
  const uint16_t* Vp = Vg + (size_t)bh * HD * SEQ;
  const unsigned char* Mp = Mg + (size_t)b * SEQ * SEQ;

  // Q A-frags, loaded once: A[m=lr][k=quad*8+j(+32)]
  int qrow = q0 + wave * 16 + lr;
  v8s qf0 = *(const v8s*)&Qp[(size_t)qrow * HD + quad * 8];
  v8s qf1 = *(const v8s*)&Qp[(size_t)qrow * HD + 32 + quad * 8];

  v4f acc_o[4];
  v4f vz = {0.f, 0.f, 0.f, 0.f};
  #pragma unroll
  for (int nt = 0; nt < 4; nt++) acc_o[nt] = vz;
  float mrow[4], lrow[4];
  #pragma unroll
  for (int r = 0; r < 4; r++) { mrow[r] = -3.0e38f; lrow[r] = 0.f; }

  for (int k0 = 0; k0 < SEQ; k0 += 64) {
    #pragma unroll
    for (int c = tid; c < 512; c += 256) {
      int row = c >> 3, seg = c & 7;
      *(uint4*)&Ks[row * 72 + seg * 8] =
          *(const uint4*)&Kp[(size_t)(k0 + row) * HD + seg * 8];
      *(uint4*)&Vs[row * 72 + seg * 8] =
          *(const uint4*)&Vp[(size_t)row * SEQ + k0 + seg * 8];
    }
    __syncthreads();

    // S = Q K^T : B-frag lane holds K[kcol=lr][d=quad*8+j(+32)]
    v4f sacc[4];
    #pragma unroll
    for (int nt = 0; nt < 4; nt++) {
      v8s kf0 = *(const v8s*)&Ks[(nt * 16 + lr) * 72 + quad * 8];
      v8s kf1 = *(const v8s*)&Ks[(nt * 16 + lr) * 72 + 32 + quad * 8];
      v4f z = vz;
      z = __builtin_amdgcn_mfma_f32_16x16x32_bf16(qf0, kf0, z, 0, 0, 0);
      z = __builtin_amdgcn_mfma_f32_16x16x32_bf16(qf1, kf1, z, 0, 0, 0);
      sacc[nt] = z;
    }

    // mask + online softmax; C-layout: col=lr (kk), row=quad*4+r (q)
    float mnew[4], alpha[4];
    #pragma unroll
    for (int r = 0; r < 4; r++) {
      int q = q0 + wave * 16 + quad * 4 + r;
      const unsigned char* mr = Mp + (size_t)q * SEQ + k0;
      float mx = -3.0e38f;
      #pragma unroll
      for (int nt = 0; nt < 4; nt++) {
        float s = sacc[nt][r] + (mr[nt * 16 + lr] ? 0.0f : -10000.0f);
        sacc[nt][r] = s;
        mx = fmaxf(mx, s);
      }
      mx = fmaxf(mx, __shfl_xor(mx, 1));
      mx = fmaxf(mx, __shfl_xor(mx, 2));
      mx = fmaxf(mx, __shfl_xor(mx, 4));
      mx = fmaxf(mx, __shfl_xor(mx, 8));
      mnew[r] = fmaxf(mrow[r], mx);
      alpha[r] = __expf(mrow[r] - mnew[r]);
      mrow[r] = mnew[r];
      float rs = 0.f;
      #pragma unroll
      for (int nt = 0; nt < 4; nt++) {
        float p = __expf(sacc[nt][r] - mnew[r]);
        sacc[nt][r] = p;
        rs += p;
      }
      rs += __shfl_xor(rs, 1);
      rs += __shfl_xor(rs, 2);
      rs += __shfl_xor(rs, 4);
      rs += __shfl_xor(rs, 8);
      lrow[r] = alpha[r] * lrow[r] + rs;
    }

    // P: C-layout -> LDS -> A-layout (per-wave region, no barrier needed)
    uint16_t* Pw = &Ps[wave * 16 * 72];
    #pragma unroll
    for (int r = 0; r < 4; r++) {
      #pragma unroll
      for (int nt = 0; nt < 4; nt++)
        Pw[(quad * 4 + r) * 72 + nt * 16 + lr] = f2bf(sacc[nt][r]);
      #pragma unroll
      for (int nt = 0; nt < 4; nt++)
        acc_o[nt][r] *= alpha[r];
    }
    v8s pf0 = *(const v8s*)&Pw[lr * 72 + quad * 8];
    v8s pf1 = *(const v8s*)&Pw[lr * 72 + 32 + quad * 8];

    // O += P V : B-frag lane holds V[kk=quad*8+j(+32)][d=nt*16+lr] = Vs[d][kk]
    #pragma unroll
    for (int nt = 0; nt < 4; nt++) {
      v8s vf0 = *(const v8s*)&Vs[(nt * 16 + lr) * 72 + quad * 8];
      v8s vf1 = *(const v8s*)&Vs[(nt * 16 + lr) * 72 + 32 + quad * 8];
      acc_o[nt] = __builtin_amdgcn_mfma_f32_16x16x32_bf16(pf0, vf0, acc_o[nt], 0, 0, 0);
      acc_o[nt] = __builtin_amdgcn_mfma_f32_16x16x32_bf16(pf1, vf1, acc_o[nt], 0, 0, 0);
    }
    __syncthreads();
  }

  #pragma unroll
  for (int nt = 0; nt < 4; nt++) {
    #pragma unroll
    for (int r = 0; r < 4; r++) {
      int q = q0 + wave * 16 + quad * 4 + r;
      float v = acc_o[nt][r] / lrow[r];
      AO[(size_t)(b * SEQ + q) * DIM + h * HD + nt * 16 + lr] = f2bf(v);
    }
  }
}

// ---------------- launch ----------------
extern "C" void kernel_launch(void* const* d_in, const int* in_sizes, int n_in,
                              void* d_out, int out_size, void* d_ws, size_t ws_size,
                              hipStream_t stream) {
  const float* from_t = (const float*)d_in[0];
  const float* to_t   = (const float*)d_in[1];
  const int*   maski  = (const int*)d_in[2];
  const float* Wq = (const float*)d_in[3];  const float* bq = (const float*)d_in[4];
  const float* Wk = (const float*)d_in[5];  const float* bk = (const float*)d_in[6];
  const float* Wv = (const float*)d_in[7];  const float* bv = (const float*)d_in[8];
  const float* Wo = (const float*)d_in[9];  const float* bo = (const float*)d_in[10];

  char* ws = (char*)d_ws;
  size_t off = 0;
  uint16_t* Xf = (uint16_t*)(ws + off); off += (size_t)MROWS * DIM * 2;   // 12.6 MB
  uint16_t* Xt = (uint16_t*)(ws + off); off += (size_t)MROWS * DIM * 2;   // 12.6 MB
  uint16_t* WT = (uint16_t*)(ws + off); off += (size_t)4 * DIM * DIM * 2; // 4.7 MB
  unsigned char* M8 = (unsigned char*)(ws + off); off += (size_t)BSZ * SEQ * SEQ; // 16.8 MB
  uint16_t* Qw = (uint16_t*)(ws + off); off += (size_t)MROWS * DIM * 2;   // [b,h,s,d]
  uint16_t* Kw = (uint16_t*)(ws + off); off += (size_t)MROWS * DIM * 2;   // [b,h,s,d]
  uint16_t* Vw = (uint16_t*)(ws + off); off += (size_t)MROWS * DIM * 2;   // [b,h,d,s]
  uint16_t* AO = (uint16_t*)(ws + off); off += (size_t)MROWS * DIM * 2;   // [m,768]
  float* Out = (float*)d_out;

  int nx4 = MROWS * DIM / 4;
  cvt_bf16_kernel<<<nx4 / 256, 256, 0, stream>>>(from_t, Xf, nx4);
  cvt_bf16_kernel<<<nx4 / 256, 256, 0, stream>>>(to_t, Xt, nx4);
  int nm4 = BSZ * SEQ * SEQ / 4;
  mask_cvt_kernel<<<nm4 / 256, 256, 0, stream>>>(maski, M8, nm4);
  wtrans_kernel<<<dim3(24, 24, 4), dim3(32, 8), 0, stream>>>(Wq, Wk, Wv, Wo, WT);

  gemm_kernel<<<dim3(64, 6, 3), 256, 0, stream>>>(Xf, Xt, WT, AO, bq, bk, bv, bo,
                                                  Qw, Kw, Vw, Out, 0);
  flash_kernel<<<dim3(SEQ / 64, BSZ * NH), 256, 0, stream>>>(Qw, Kw, Vw, M8, AO);
  gemm_kernel<<<dim3(64, 6, 1), 256, 0, stream>>>(Xf, Xt, WT, AO, bq, bk, bv, bo,
                                                  Qw, Kw, Vw, Out, 3);
}

// Round 2
// 394.114 us; speedup vs baseline: 1.1438x; 1.1438x over previous
//
#include <hip/hip_runtime.h>
#include <stdint.h>

#define DIM 768
#define NH 12
#define HD 64
#define BSZ 4
#define SEQ 2048
#define MROWS (BSZ*SEQ)   // 8192

typedef __attribute__((ext_vector_type(8))) short v8s;   // 8 bf16 (4 VGPRs)
typedef __attribute__((ext_vector_type(4))) float v4f;   // 4 fp32 acc

__device__ __forceinline__ uint16_t f2bf(float x) {
  union { float f; uint32_t u; } v; v.f = x;
  uint32_t r = v.u + 0x7fffu + ((v.u >> 16) & 1u);   // RNE
  return (uint16_t)(r >> 16);
}

// packed fp32x2 -> bf16x2 (HW v_cvt_pk_bf16_f32 on gfx950; software fallback)
#if __has_builtin(__builtin_amdgcn_cvt_pk_bf16_f32)
typedef __attribute__((ext_vector_type(2))) __bf16 v2bf;
__device__ __forceinline__ uint32_t pack_bf16(float a, float b) {
  union { v2bf v; uint32_t u; } c;
  c.v = __builtin_amdgcn_cvt_pk_bf16_f32(a, b);
  return c.u;
}
#else
__device__ __forceinline__ uint32_t pack_bf16(float a, float b) {
  return (uint32_t)f2bf(a) | ((uint32_t)f2bf(b) << 16);
}
#endif

__device__ __forceinline__ float fexp2(float x) {
#if __has_builtin(__builtin_amdgcn_exp2f)
  return __builtin_amdgcn_exp2f(x);
#else
  return exp2f(x);
#endif
}

// ---------------- pre-pass: fp32 -> bf16 (vectorized) ----------------
__global__ void cvt_bf16_kernel(const float* __restrict__ src,
                                uint16_t* __restrict__ dst, int n4) {
  int i = blockIdx.x * blockDim.x + threadIdx.x;
  if (i >= n4) return;
  float4 v = ((const float4*)src)[i];
  ushort4 o;
  o.x = f2bf(v.x); o.y = f2bf(v.y); o.z = f2bf(v.z); o.w = f2bf(v.w);
  ((ushort4*)dst)[i] = o;
}

// ---------------- pre-pass: mask int32 -> u64 bitmask [b][kt][q] ----------------
// word (b,kt,q): bit j = mask[b][q][kt*64+j] != 0.  2 MB total -> L2-resident.
__global__ void mask_bits_kernel(const int* __restrict__ src,
                                 unsigned long long* __restrict__ dst, int nwords) {
  int gtid = blockIdx.x * blockDim.x + threadIdx.x;
  int w = gtid >> 6;
  int lane = threadIdx.x & 63;
  if (w >= nwords) return;
  int b  = w >> 16;          // 2048*32 words per batch
  int q  = (w >> 5) & 2047;
  int kt = w & 31;           // kt fastest -> fully coalesced 256B reads per wave
  int m = src[((size_t)b * SEQ + q) * SEQ + kt * 64 + lane];
  unsigned long long bits = __ballot(m != 0);
  if (lane == 0) dst[((size_t)b * 32 + kt) * SEQ + q] = bits;
}

// ---------------- pre-pass: W [K][N] fp32 -> WT [N][K] bf16 ----------------
__global__ void wtrans_kernel(const float* __restrict__ Wq, const float* __restrict__ Wk,
                              const float* __restrict__ Wv, const float* __restrict__ Wo,
                              uint16_t* __restrict__ WT) {
  __shared__ float tile[32][33];
  int z = blockIdx.z;
  const float* src = (z==0) ? Wq : (z==1) ? Wk : (z==2) ? Wv : Wo;
  uint16_t* dst = WT + (size_t)z * DIM * DIM;
  int tx = threadIdx.x, ty = threadIdx.y;
  int x  = blockIdx.x * 32 + tx;
  int y0 = blockIdx.y * 32;
  for (int j = ty; j < 32; j += 8)
    tile[j][tx] = src[(size_t)(y0 + j) * DIM + x];
  __syncthreads();
  int xo = y0 + tx;
  for (int j = ty; j < 32; j += 8)
    dst[(size_t)(blockIdx.x * 32 + j) * DIM + xo] = f2bf(tile[tx][j]);
}

// ---------------- GEMM: C[M=8192,N=768] = A(bf16) @ WT^T + bias ----------------
// mode 0: Q -> Qw [b,h,s,d] * (SCALE*log2e)   mode 1: K -> Kw [b,h,s,d]
// mode 2: V -> Vw [b,h,d,s] (transposed)      mode 3: O -> d_out fp32 [m,n]
__global__ __launch_bounds__(256) void gemm_kernel(
    const uint16_t* __restrict__ Xf, const uint16_t* __restrict__ Xt,
    const uint16_t* __restrict__ WT, const uint16_t* __restrict__ AO,
    const float* __restrict__ bq, const float* __restrict__ bk,
    const float* __restrict__ bv, const float* __restrict__ bo,
    uint16_t* __restrict__ Qw, uint16_t* __restrict__ Kw, uint16_t* __restrict__ Vw,
    float* __restrict__ Out, int mode_base)
{
  __shared__ alignas(16) uint16_t As[128 * 56];
  __shared__ alignas(16) uint16_t Bs[128 * 56];
  int mode = mode_base + blockIdx.z;
  const uint16_t* A = (mode == 0) ? Xf : (mode == 3 ? AO : Xt);
  const uint16_t* W = WT + (size_t)mode * DIM * DIM;
  const float* bias = (mode == 0) ? bq : (mode == 1) ? bk : (mode == 2) ? bv : bo;

  int m0 = blockIdx.x * 128, n0 = blockIdx.y * 128;
  int tid = threadIdx.x;
  int wave = tid >> 6, lane = tid & 63, lr = lane & 15, quad = lane >> 4;
  int wm = (wave >> 1) * 64, wn = (wave & 1) * 64;

  v4f acc[4][4];
  v4f vz = {0.f, 0.f, 0.f, 0.f};
  #pragma unroll
  for (int i = 0; i < 4; i++)
    #pragma unroll
    for (int j = 0; j < 4; j++) acc[i][j] = vz;

  for (int k0 = 0; k0 < DIM; k0 += 32) {
    #pragma unroll
    for (int c = tid; c < 512; c += 256) {
      int row = c >> 2, seg = c & 3;
      *(uint4*)&As[row * 56 + seg * 8] =
          *(const uint4*)&A[(size_t)(m0 + row) * DIM + k0 + seg * 8];
      *(uint4*)&Bs[row * 56 + seg * 8] =
          *(const uint4*)&W[(size_t)(n0 + row) * DIM + k0 + seg * 8];
    }
    __syncthreads();
    v8s af[4], bfr[4];
    #pragma unroll
    for (int i = 0; i < 4; i++)
      af[i] = *(const v8s*)&As[(wm + i * 16 + lr) * 56 + quad * 8];
    #pragma unroll
    for (int j = 0; j < 4; j++)
      bfr[j] = *(const v8s*)&Bs[(wn + j * 16 + lr) * 56 + quad * 8];
    #pragma unroll
    for (int i = 0; i < 4; i++)
      #pragma unroll
      for (int j = 0; j < 4; j++)
        acc[i][j] = __builtin_amdgcn_mfma_f32_16x16x32_bf16(af[i], bfr[j], acc[i][j], 0, 0, 0);
    __syncthreads();
  }

  float bj[4];
  #pragma unroll
  for (int j = 0; j < 4; j++) bj[j] = bias[n0 + wn + j * 16 + lr];

  if (mode == 3) {
    #pragma unroll
    for (int i = 0; i < 4; i++) {
      int m = m0 + wm + i * 16 + quad * 4;
      #pragma unroll
      for (int j = 0; j < 4; j++) {
        int n = n0 + wn + j * 16 + lr;
        #pragma unroll
        for (int r = 0; r < 4; r++)
          Out[(size_t)(m + r) * DIM + n] = acc[i][j][r] + bj[j];
      }
    }
  } else if (mode == 2) {
    #pragma unroll
    for (int i = 0; i < 4; i++) {
      int m = m0 + wm + i * 16 + quad * 4;
      int b = m >> 11, s = m & 2047;
      #pragma unroll
      for (int j = 0; j < 4; j++) {
        int n = n0 + wn + j * 16 + lr;
        int h = n >> 6, d = n & 63;
        uint2 pk;
        pk.x = pack_bf16(acc[i][j][0] + bj[j], acc[i][j][1] + bj[j]);
        pk.y = pack_bf16(acc[i][j][2] + bj[j], acc[i][j][3] + bj[j]);
        *(uint2*)&Vw[(size_t)((b * NH + h) * HD + d) * SEQ + s] = pk;  // s 4-aligned
      }
    }
  } else {
    uint16_t* Dst = (mode == 0) ? Qw : Kw;
    float scale = (mode == 0) ? 0.18033688f : 1.0f;   // HD^-0.5 * log2(e) folded into Q
    #pragma unroll
    for (int i = 0; i < 4; i++) {
      int m = m0 + wm + i * 16 + quad * 4;
      int b = m >> 11, s0 = m & 2047;
      #pragma unroll
      for (int j = 0; j < 4; j++) {
        int n = n0 + wn + j * 16 + lr;
        int h = n >> 6, d = n & 63;
        #pragma unroll
        for (int r = 0; r < 4; r++) {
          float v = (acc[i][j][r] + bj[j]) * scale;
          Dst[(size_t)((b * NH + h) * SEQ + (s0 + r)) * HD + d] = f2bf(v);
        }
      }
    }
  }
}

// ---------------- flash attention: no-max softmax + bitmask + XOR-swizzled LDS ----
// LDS layout: stride 64, chunk(16B) swizzled by chunk' = chunk ^ (row & 7).
// b128 reads/writes run at the LDS bandwidth floor (8 lanes/chunk group).
__global__ __launch_bounds__(256) void flash_kernel(
    const uint16_t* __restrict__ Qg, const uint16_t* __restrict__ Kg,
    const uint16_t* __restrict__ Vg, const unsigned long long* __restrict__ Mb,
    uint16_t* __restrict__ AO)
{
  __shared__ alignas(16) uint16_t Ks[64 * 64];
  __shared__ alignas(16) uint16_t Vs[64 * 64];       // V^T: [d][kk]
  __shared__ alignas(16) uint16_t Ps[4 * 16 * 64];   // per-wave P round-trip

  int tid = threadIdx.x, wave = tid >> 6, lane = tid & 63, lr = lane & 15, quad = lane >> 4;
  int bh = blockIdx.y;
  int b = bh / NH, h = bh - b * NH;
  int q0 = blockIdx.x * 64;
  const uint16_t* Qp = Qg + (size_t)bh * SEQ * HD;
  const uint16_t* Kp = Kg + (size_t)bh * SEQ * HD;
  const uint16_t* Vp = Vg + (size_t)bh * HD * SEQ;
  // mask words for this lane's 4 C-rows (q0+wave*16+quad*4 .. +3), tile-major layout
  const unsigned long long* Mp = Mb + (size_t)b * 32 * SEQ + (q0 + wave * 16 + quad * 4);

  int swk = lr & 7;

  // Q A-frags, loaded once: A[m=lr][k=quad*8+j(+32)]
  int qrow = q0 + wave * 16 + lr;
  v8s qf0 = *(const v8s*)&Qp[(size_t)qrow * HD + quad * 8];
  v8s qf1 = *(const v8s*)&Qp[(size_t)qrow * HD + 32 + quad * 8];

  v4f acc_o[4];
  v4f vz = {0.f, 0.f, 0.f, 0.f};
  #pragma unroll
  for (int nt = 0; nt < 4; nt++) acc_o[nt] = vz;
  float lsum[4] = {0.f, 0.f, 0.f, 0.f};

  for (int k0 = 0; k0 < SEQ; k0 += 64) {
    #pragma unroll
    for (int c = tid; c < 512; c += 256) {
      int row = c >> 3, seg = c & 7;
      int sk = ((seg ^ (row & 7)) << 3);
      *(uint4*)&Ks[row * 64 + sk] =
          *(const uint4*)&Kp[(size_t)(k0 + row) * HD + seg * 8];
      *(uint4*)&Vs[row * 64 + sk] =
          *(const uint4*)&Vp[(size_t)row * SEQ + k0 + seg * 8];
    }
    // mask words (independent of LDS; overlap latency with the barrier)
    const unsigned long long* mp = Mp + (size_t)(k0 >> 6) * SEQ;
    ulonglong2 ma = *(const ulonglong2*)mp;
    ulonglong2 mc = *(const ulonglong2*)(mp + 2);
    __syncthreads();

    // S = Q K^T
    v4f sacc[4];
    #pragma unroll
    for (int nt = 0; nt < 4; nt++) {
      int rowb = (nt * 16 + lr) * 64;
      v8s kf0 = *(const v8s*)&Ks[rowb + ((quad ^ swk) << 3)];
      v8s kf1 = *(const v8s*)&Ks[rowb + (((quad + 4) ^ swk) << 3)];
      v4f z = vz;
      z = __builtin_amdgcn_mfma_f32_16x16x32_bf16(qf0, kf0, z, 0, 0, 0);
      z = __builtin_amdgcn_mfma_f32_16x16x32_bf16(qf1, kf1, z, 0, 0, 0);
      sacc[nt] = z;
    }

    // no-max softmax: p = 2^s * maskbit (Q pre-scaled by log2e; masked -> exact 0)
    uint16_t* Pw = &Ps[wave * 1024];
    #pragma unroll
    for (int r = 0; r < 4; r++) {
      unsigned long long mw = (r < 2) ? ((r & 1) ? ma.y : ma.x)
                                      : ((r & 1) ? mc.y : mc.x);
      uint32_t wlo = (uint32_t)mw, whi = (uint32_t)(mw >> 32);
      float ps[4];
      #pragma unroll
      for (int nt = 0; nt < 4; nt++) {
        uint32_t wsel = (nt < 2) ? wlo : whi;
        int sh = ((nt & 1) << 4) + lr;
        float bit = (float)((wsel >> sh) & 1u);
        float p = fexp2(sacc[nt][r]) * bit;
        ps[nt] = p;
        lsum[r] += p;
      }
      uint32_t p01 = pack_bf16(ps[0], ps[1]);
      uint32_t p23 = pack_bf16(ps[2], ps[3]);
      int rw = quad * 4 + r, key = rw & 7, cb = lr >> 3, co = lr & 7;
      uint16_t* Prow = &Pw[rw * 64];
      Prow[(((cb    ) ^ key) << 3) + co] = (uint16_t)p01;
      Prow[(((cb + 2) ^ key) << 3) + co] = (uint16_t)(p01 >> 16);
      Prow[(((cb + 4) ^ key) << 3) + co] = (uint16_t)p23;
      Prow[(((cb + 6) ^ key) << 3) + co] = (uint16_t)(p23 >> 16);
    }
    v8s pf0 = *(const v8s*)&Pw[lr * 64 + ((quad ^ swk) << 3)];
    v8s pf1 = *(const v8s*)&Pw[lr * 64 + (((quad + 4) ^ swk) << 3)];

    // O += P V
    #pragma unroll
    for (int nt = 0; nt < 4; nt++) {
      int rowb = (nt * 16 + lr) * 64;
      v8s vf0 = *(const v8s*)&Vs[rowb + ((quad ^ swk) << 3)];
      v8s vf1 = *(const v8s*)&Vs[rowb + (((quad + 4) ^ swk) << 3)];
      acc_o[nt] = __builtin_amdgcn_mfma_f32_16x16x32_bf16(pf0, vf0, acc_o[nt], 0, 0, 0);
      acc_o[nt] = __builtin_amdgcn_mfma_f32_16x16x32_bf16(pf1, vf1, acc_o[nt], 0, 0, 0);
    }
    __syncthreads();
  }

  // deferred sum reduction across the 16 lr lanes, then normalize
  float rinv[4];
  #pragma unroll
  for (int r = 0; r < 4; r++) {
    float ls = lsum[r];
    ls += __shfl_xor(ls, 1);
    ls += __shfl_xor(ls, 2);
    ls += __shfl_xor(ls, 4);
    ls += __shfl_xor(ls, 8);
    rinv[r] = 1.0f / ls;
  }
  #pragma unroll
  for (int nt = 0; nt < 4; nt++) {
    #pragma unroll
    for (int r = 0; r < 4; r++) {
      int q = q0 + wave * 16 + quad * 4 + r;
      float v = acc_o[nt][r] * rinv[r];
      AO[(size_t)(b * SEQ + q) * DIM + h * HD + nt * 16 + lr] = f2bf(v);
    }
  }
}

// ---------------- launch ----------------
extern "C" void kernel_launch(void* const* d_in, const int* in_sizes, int n_in,
                              void* d_out, int out_size, void* d_ws, size_t ws_size,
                              hipStream_t stream) {
  const float* from_t = (const float*)d_in[0];
  const float* to_t   = (const float*)d_in[1];
  const int*   maski  = (const int*)d_in[2];
  const float* Wq = (const float*)d_in[3];  const float* bq = (const float*)d_in[4];
  const float* Wk = (const float*)d_in[5];  const float* bk = (const float*)d_in[6];
  const float* Wv = (const float*)d_in[7];  const float* bv = (const float*)d_in[8];
  const float* Wo = (const float*)d_in[9];  const float* bo = (const float*)d_in[10];

  char* ws = (char*)d_ws;
  size_t off = 0;
  uint16_t* Xf = (uint16_t*)(ws + off); off += (size_t)MROWS * DIM * 2;
  uint16_t* Xt = (uint16_t*)(ws + off); off += (size_t)MROWS * DIM * 2;
  uint16_t* WT = (uint16_t*)(ws + off); off += (size_t)4 * DIM * DIM * 2;
  unsigned long long* Mbits = (unsigned long long*)(ws + off);
  off += (size_t)BSZ * 32 * SEQ * 8;                                   // 2 MB
  uint16_t* Qw = (uint16_t*)(ws + off); off += (size_t)MROWS * DIM * 2; // [b,h,s,d]
  uint16_t* Kw = (uint16_t*)(ws + off); off += (size_t)MROWS * DIM * 2; // [b,h,s,d]
  uint16_t* Vw = (uint16_t*)(ws + off); off += (size_t)MROWS * DIM * 2; // [b,h,d,s]
  uint16_t* AO = (uint16_t*)(ws + off); off += (size_t)MROWS * DIM * 2; // [m,768]
  float* Out = (float*)d_out;

  int nx4 = MROWS * DIM / 4;
  cvt_bf16_kernel<<<nx4 / 256, 256, 0, stream>>>(from_t, Xf, nx4);
  cvt_bf16_kernel<<<nx4 / 256, 256, 0, stream>>>(to_t, Xt, nx4);
  int nwords = BSZ * 32 * SEQ;                       // 262144
  mask_bits_kernel<<<nwords * 64 / 256, 256, 0, stream>>>(maski, Mbits, nwords);
  wtrans_kernel<<<dim3(24, 24, 4), dim3(32, 8), 0, stream>>>(Wq, Wk, Wv, Wo, WT);

  gemm_kernel<<<dim3(64, 6, 3), 256, 0, stream>>>(Xf, Xt, WT, AO, bq, bk, bv, bo,
                                                  Qw, Kw, Vw, Out, 0);
  flash_kernel<<<dim3(SEQ / 64, BSZ * NH), 256, 0, stream>>>(Qw, Kw, Vw, Mbits, AO);
  gemm_kernel<<<dim3(64, 6, 1), 256, 0, stream>>>(Xf, Xt, WT, AO, bq, bk, bv, bo,
                                                  Qw, Kw, Vw, Out, 3);
}

// Round 5
// 354.074 us; speedup vs baseline: 1.2732x; 1.1131x over previous
//
#include <hip/hip_runtime.h>
#include <stdint.h>

#define DIM 768
#define NH 12
#define HD 64
#define BSZ 4
#define SEQ 2048
#define MROWS (BSZ*SEQ)   // 8192

typedef __attribute__((ext_vector_type(8))) short v8s;        // 8 bf16 (4 VGPRs)
typedef __attribute__((ext_vector_type(4))) float v4f;        // 4 fp32 acc
typedef __attribute__((ext_vector_type(4))) _Float16 v4h;     // 4 f16 (2 VGPRs)
typedef __attribute__((ext_vector_type(2))) __fp16 v2fp;      // cvt_pkrtz native type

__device__ __forceinline__ uint16_t f2bf(float x) {
  union { float f; uint32_t u; } v; v.f = x;
  uint32_t r = v.u + 0x7fffu + ((v.u >> 16) & 1u);   // RNE
  return (uint16_t)(r >> 16);
}

#if __has_builtin(__builtin_amdgcn_cvt_pk_bf16_f32)
typedef __attribute__((ext_vector_type(2))) __bf16 v2bf;
__device__ __forceinline__ uint32_t pack_bf16(float a, float b) {
  union { v2bf v; uint32_t u; } c;
  c.v = __builtin_amdgcn_cvt_pk_bf16_f32(a, b);
  return c.u;
}
#else
__device__ __forceinline__ uint32_t pack_bf16(float a, float b) {
  return (uint32_t)f2bf(a) | ((uint32_t)f2bf(b) << 16);
}
#endif

__device__ __forceinline__ uint32_t pack_f16(float a, float b) {
#if __has_builtin(__builtin_amdgcn_cvt_pkrtz)
  union { v2fp h; uint32_t u; } c;
  c.h = __builtin_amdgcn_cvt_pkrtz(a, b);
  return c.u;
#else
  union { _Float16 h[2]; uint32_t u; } c;
  c.h[0] = (_Float16)a; c.h[1] = (_Float16)b; return c.u;
#endif
}

__device__ __forceinline__ float fexp2(float x) {
#if __has_builtin(__builtin_amdgcn_exp2f)
  return __builtin_amdgcn_exp2f(x);
#else
  return exp2f(x);
#endif
}

// async global->LDS, 16B per lane; LDS dst = wave-uniform base + lane*16
__device__ __forceinline__ void gl16(const void* g, void* l) {
  __builtin_amdgcn_global_load_lds(
      (const __attribute__((address_space(1))) unsigned int*)g,
      (__attribute__((address_space(3))) unsigned int*)l, 16, 0, 0);
}

// ---------------- pre-pass: fp32 -> bf16 (both X tensors, one launch) ----------
__global__ void cvt_bf16_kernel(const float* __restrict__ src0, uint16_t* __restrict__ dst0,
                                const float* __restrict__ src1, uint16_t* __restrict__ dst1,
                                int n4) {
  int i = blockIdx.x * blockDim.x + threadIdx.x;
  const float* src = (i < n4) ? src0 : src1;
  uint16_t* dst = (i < n4) ? dst0 : dst1;
  int j = (i < n4) ? i : i - n4;
  float4 v = ((const float4*)src)[j];
  ushort4 o;
  o.x = f2bf(v.x); o.y = f2bf(v.y); o.z = f2bf(v.z); o.w = f2bf(v.w);
  ((ushort4*)dst)[j] = o;
}

// ---------------- pre-pass: mask int32 -> u64 bitmask [b][kt][q] ----------------
__global__ void mask_bits_kernel(const int* __restrict__ src,
                                 unsigned long long* __restrict__ dst, int nwords) {
  int gtid = blockIdx.x * blockDim.x + threadIdx.x;
  int w = gtid >> 6;
  int lane = threadIdx.x & 63;
  if (w >= nwords) return;
  int b  = w >> 16;
  int q  = (w >> 5) & 2047;
  int kt = w & 31;
  int m = src[((size_t)b * SEQ + q) * SEQ + kt * 64 + lane];
  unsigned long long bits = __ballot(m != 0);
  if (lane == 0) dst[((size_t)b * 32 + kt) * SEQ + q] = bits;
}

// ---------------- pre-pass: W [K][N] fp32 -> WT [N][K] bf16 ----------------
__global__ void wtrans_kernel(const float* __restrict__ Wq, const float* __restrict__ Wk,
                              const float* __restrict__ Wv, const float* __restrict__ Wo,
                              uint16_t* __restrict__ WT) {
  __shared__ float tile[32][33];
  int z = blockIdx.z;
  const float* src = (z==0) ? Wq : (z==1) ? Wk : (z==2) ? Wv : Wo;
  uint16_t* dst = WT + (size_t)z * DIM * DIM;
  int tx = threadIdx.x, ty = threadIdx.y;
  int x  = blockIdx.x * 32 + tx;
  int y0 = blockIdx.y * 32;
  for (int j = ty; j < 32; j += 8)
    tile[j][tx] = src[(size_t)(y0 + j) * DIM + x];
  __syncthreads();
  int xo = y0 + tx;
  for (int j = ty; j < 32; j += 8)
    dst[(size_t)(blockIdx.x * 32 + j) * DIM + xo] = f2bf(tile[tx][j]);
}

// ---------------- GEMM: C[M=8192,N=768] = A(bf16) @ WT^T + bias ----------------
// mode 0: Q -> Qw [b,h,s,d] * (SCALE*log2e), natural layout (bf16)
// mode 1: K -> Kw [b,h,s,d], d-chunks XOR-swizzled by (s&7)  (bf16)
// mode 2: V -> Vw [b,h,d,s] f16, s-chunks XOR-swizzled by (d&7)
// mode 3: O -> d_out fp32 [m,n]
__global__ __launch_bounds__(256) void gemm_kernel(
    const uint16_t* __restrict__ Xf, const uint16_t* __restrict__ Xt,
    const uint16_t* __restrict__ WT, const uint16_t* __restrict__ AO,
    const float* __restrict__ bq, const float* __restrict__ bk,
    const float* __restrict__ bv, const float* __restrict__ bo,
    uint16_t* __restrict__ Qw, uint16_t* __restrict__ Kw, uint16_t* __restrict__ Vw,
    float* __restrict__ Out, int mode_base)
{
  __shared__ alignas(16) uint16_t As[128 * 56];
  __shared__ alignas(16) uint16_t Bs[128 * 56];
  int mode = mode_base + blockIdx.z;
  const uint16_t* A = (mode == 0) ? Xf : (mode == 3 ? AO : Xt);
  const uint16_t* W = WT + (size_t)mode * DIM * DIM;
  const float* bias = (mode == 0) ? bq : (mode == 1) ? bk : (mode == 2) ? bv : bo;

  int m0 = blockIdx.x * 128, n0 = blockIdx.y * 128;
  int tid = threadIdx.x;
  int wave = tid >> 6, lane = tid & 63, lr = lane & 15, quad = lane >> 4;
  int wm = (wave >> 1) * 64, wn = (wave & 1) * 64;

  v4f acc[4][4];
  v4f vz = {0.f, 0.f, 0.f, 0.f};
  #pragma unroll
  for (int i = 0; i < 4; i++)
    #pragma unroll
    for (int j = 0; j < 4; j++) acc[i][j] = vz;

  for (int k0 = 0; k0 < DIM; k0 += 32) {
    #pragma unroll
    for (int c = tid; c < 512; c += 256) {
      int row = c >> 2, seg = c & 3;
      *(uint4*)&As[row * 56 + seg * 8] =
          *(const uint4*)&A[(size_t)(m0 + row) * DIM + k0 + seg * 8];
      *(uint4*)&Bs[row * 56 + seg * 8] =
          *(const uint4*)&W[(size_t)(n0 + row) * DIM + k0 + seg * 8];
    }
    __syncthreads();
    v8s af[4], bfr[4];
    #pragma unroll
    for (int i = 0; i < 4; i++)
      af[i] = *(const v8s*)&As[(wm + i * 16 + lr) * 56 + quad * 8];
    #pragma unroll
    for (int j = 0; j < 4; j++)
      bfr[j] = *(const v8s*)&Bs[(wn + j * 16 + lr) * 56 + quad * 8];
    #pragma unroll
    for (int i = 0; i < 4; i++)
      #pragma unroll
      for (int j = 0; j < 4; j++)
        acc[i][j] = __builtin_amdgcn_mfma_f32_16x16x32_bf16(af[i], bfr[j], acc[i][j], 0, 0, 0);
    __syncthreads();
  }

  float bj[4];
  #pragma unroll
  for (int j = 0; j < 4; j++) bj[j] = bias[n0 + wn + j * 16 + lr];

  if (mode == 3) {
    #pragma unroll
    for (int i = 0; i < 4; i++) {
      int m = m0 + wm + i * 16 + quad * 4;
      #pragma unroll
      for (int j = 0; j < 4; j++) {
        int n = n0 + wn + j * 16 + lr;
        #pragma unroll
        for (int r = 0; r < 4; r++)
          Out[(size_t)(m + r) * DIM + n] = acc[i][j][r] + bj[j];
      }
    }
  } else if (mode == 2) {
    // Vw f16 [b,h,d,s], s-chunk swizzled by d&7
    #pragma unroll
    for (int i = 0; i < 4; i++) {
      int m = m0 + wm + i * 16 + quad * 4;
      int b = m >> 11, s = m & 2047;   // s 4-aligned
      #pragma unroll
      for (int j = 0; j < 4; j++) {
        int n = n0 + wn + j * 16 + lr;
        int h = n >> 6, d = n & 63;
        uint2 pk;
        pk.x = pack_f16(acc[i][j][0] + bj[j], acc[i][j][1] + bj[j]);
        pk.y = pack_f16(acc[i][j][2] + bj[j], acc[i][j][3] + bj[j]);
        int pos = (s & ~63) + ((((s >> 3) & 7) ^ (d & 7)) << 3) + (s & 7);
        *(uint2*)&Vw[((size_t)(b * NH + h) * HD + d) * SEQ + pos] = pk;
      }
    }
  } else {
    uint16_t* Dst = (mode == 0) ? Qw : Kw;
    float scale = (mode == 0) ? 0.18033688f : 1.0f;   // HD^-0.5 * log2(e) folded into Q
    #pragma unroll
    for (int i = 0; i < 4; i++) {
      int m = m0 + wm + i * 16 + quad * 4;
      int b = m >> 11, s0 = m & 2047;
      #pragma unroll
      for (int j = 0; j < 4; j++) {
        int n = n0 + wn + j * 16 + lr;
        int h = n >> 6, d = n & 63;
        #pragma unroll
        for (int r = 0; r < 4; r++) {
          float v = (acc[i][j][r] + bj[j]) * scale;
          int s = s0 + r;
          int dd = (mode == 1) ? ((((d >> 3) ^ (s & 7)) << 3) + (d & 7)) : d;
          Dst[((size_t)(b * NH + h) * SEQ + s) * HD + dd] = f2bf(v);
        }
      }
    }
  }
}

// ---------------- flash attention: S^T trick, P stays in registers ---------------
// S^T = K·Q^T (C-layout: lane lr owns q=lr, kk=nt*16+quad*4+r). Those 4 regs per nt
// ARE the B-frag of mfma_f32_16x16x16f16 -> PV directly from registers (no P LDS).
// p = 2^(s-8): bias keeps p in f16 range (max |s|~17 > 16 = f16 overflow); the
// 2^-8 factor cancels in O = sum(p v)/sum(p).
__global__ __launch_bounds__(256) void flash_kernel(
    const uint16_t* __restrict__ Qg, const uint16_t* __restrict__ Kg,
    const uint16_t* __restrict__ Vg, const unsigned long long* __restrict__ Mb,
    uint16_t* __restrict__ AO)
{
  __shared__ alignas(16) uint16_t Ks[64 * 64];   // 8 KB, swizzle baked in global Kw
  __shared__ alignas(16) uint16_t Vs[64 * 64];   // 8 KB f16 bits, swizzle baked in Vw

  int tid = threadIdx.x, wave = tid >> 6, lane = tid & 63, lr = lane & 15, quad = lane >> 4;
  int bh = blockIdx.y;
  int b = bh / NH, h = bh - b * NH;
  int q0 = blockIdx.x * 64;
  const uint16_t* Qp = Qg + (size_t)bh * SEQ * HD;
  const uint16_t* Kp = Kg + (size_t)bh * SEQ * HD;
  const uint16_t* Vp = Vg + (size_t)bh * HD * SEQ;
  int qg = q0 + wave * 16 + lr;                    // this lane's q (C-columns)
  const unsigned long long* Mp = Mb + (size_t)b * 32 * SEQ + qg;

  int swk = lr & 7, sh0 = quad * 4;

  // Q B-frags (16x16x32): lane n=lr holds Q[q=lr][d=quad*8+j(+32)] — natural layout
  v8s qf0 = *(const v8s*)&Qp[(size_t)qg * HD + quad * 8];
  v8s qf1 = *(const v8s*)&Qp[(size_t)qg * HD + 32 + quad * 8];

  // DMA source pointers (lane-linear 16B chunks; swizzle already in global layout)
  const uint16_t* kgl = Kp + ((size_t)(wave * 16 + (lane >> 3)) * HD + (lane & 7) * 8);
  const uint16_t* vgl = Vp + ((size_t)(wave * 16 + (lane >> 3)) * SEQ + (lane & 7) * 8);

  v4f acc_o[4];
  v4f vz = {0.f, 0.f, 0.f, 0.f};
  #pragma unroll
  for (int dt = 0; dt < 4; dt++) acc_o[dt] = vz;
  float lsum = 0.f;

  for (int k0 = 0; k0 < SEQ; k0 += 64) {
    __syncthreads();                               // prev tile's LDS reads done
    gl16(kgl + (size_t)k0 * HD,       &Ks[wave * 1024]);
    gl16(kgl + (size_t)k0 * HD + 512, &Ks[wave * 1024 + 512]);
    gl16(vgl + k0,                    &Vs[wave * 1024]);
    gl16(vgl + k0 + 8 * SEQ,          &Vs[wave * 1024 + 512]);
    unsigned long long mw = Mp[(size_t)(k0 >> 6) * SEQ];
    uint32_t mlo = (uint32_t)mw, mhi = (uint32_t)(mw >> 32);
    __syncthreads();                               // DMA complete (vmcnt(0)+barrier)

    // S^T = K·Q^T : A-frag = K rows (kk = nt*16+lr), B-frag = qf
    v4f sacc[4];
    #pragma unroll
    for (int nt = 0; nt < 4; nt++) {
      int rowb = (nt * 16 + lr) << 6;
      v8s kf0 = *(const v8s*)&Ks[rowb + ((quad ^ swk) << 3)];
      v8s kf1 = *(const v8s*)&Ks[rowb + (((quad + 4) ^ swk) << 3)];
      v4f z = vz;
      z = __builtin_amdgcn_mfma_f32_16x16x32_bf16(kf0, qf0, z, 0, 0, 0);
      z = __builtin_amdgcn_mfma_f32_16x16x32_bf16(kf1, qf1, z, 0, 0, 0);
      sacc[nt] = z;
    }

    // softmax (no-max): p = 2^(s-8) * maskbit; pack straight into PV B-frags
    v4h pf[4];
    #pragma unroll
    for (int nt = 0; nt < 4; nt++) {
      uint32_t b4 = ((nt < 2 ? mlo : mhi) >> (sh0 + ((nt & 1) << 4))) & 15u;
      float p0 = fexp2(sacc[nt][0] - 8.0f) * (float)(b4 & 1u);
      float p1 = fexp2(sacc[nt][1] - 8.0f) * (float)((b4 >> 1) & 1u);
      float p2 = fexp2(sacc[nt][2] - 8.0f) * (float)((b4 >> 2) & 1u);
      float p3 = fexp2(sacc[nt][3] - 8.0f) * (float)((b4 >> 3) & 1u);
      lsum += (p0 + p1) + (p2 + p3);
      union { uint2 u; v4h h; } c;
      c.u.x = pack_f16(p0, p1);
      c.u.y = pack_f16(p2, p3);
      pf[nt] = c.h;
    }

    // O^T += V^T·P^T : A-frag = Vs[d=dt*16+lr][kk=nt*16+quad*4+j] (b64 reads)
    #pragma unroll
    for (int dt = 0; dt < 4; dt++) {
      int rowb = (dt * 16 + lr) << 6;
      #pragma unroll
      for (int nt = 0; nt < 4; nt++) {
        int ch = ((nt * 2 + (quad >> 1)) ^ swk) << 3;
        v4h vf = *(const v4h*)&Vs[rowb + ch + ((quad & 1) << 2)];
        acc_o[dt] = __builtin_amdgcn_mfma_f32_16x16x16f16(vf, pf[nt], acc_o[dt], 0, 0, 0);
      }
    }
  }

  // reduce lsum over the 4 quad-groups holding the same q
  lsum += __shfl_xor(lsum, 16);
  lsum += __shfl_xor(lsum, 32);
  float rinv = 1.0f / lsum;

  #pragma unroll
  for (int dt = 0; dt < 4; dt++) {
    float o0 = acc_o[dt][0] * rinv, o1 = acc_o[dt][1] * rinv;
    float o2 = acc_o[dt][2] * rinv, o3 = acc_o[dt][3] * rinv;
    uint2 pk;
    pk.x = pack_bf16(o0, o1);
    pk.y = pack_bf16(o2, o3);
    *(uint2*)&AO[(size_t)(b * SEQ + qg) * DIM + h * HD + dt * 16 + sh0] = pk;
  }
}

// ---------------- launch ----------------
extern "C" void kernel_launch(void* const* d_in, const int* in_sizes, int n_in,
                              void* d_out, int out_size, void* d_ws, size_t ws_size,
                              hipStream_t stream) {
  const float* from_t = (const float*)d_in[0];
  const float* to_t   = (const float*)d_in[1];
  const int*   maski  = (const int*)d_in[2];
  const float* Wq = (const float*)d_in[3];  const float* bq = (const float*)d_in[4];
  const float* Wk = (const float*)d_in[5];  const float* bk = (const float*)d_in[6];
  const float* Wv = (const float*)d_in[7];  const float* bv = (const float*)d_in[8];
  const float* Wo = (const float*)d_in[9];  const float* bo = (const float*)d_in[10];

  char* ws = (char*)d_ws;
  size_t off = 0;
  uint16_t* Xf = (uint16_t*)(ws + off); off += (size_t)MROWS * DIM * 2;
  uint16_t* Xt = (uint16_t*)(ws + off); off += (size_t)MROWS * DIM * 2;
  uint16_t* WT = (uint16_t*)(ws + off); off += (size_t)4 * DIM * DIM * 2;
  unsigned long long* Mbits = (unsigned long long*)(ws + off);
  off += (size_t)BSZ * 32 * SEQ * 8;                                    // 2 MB
  uint16_t* Qw = (uint16_t*)(ws + off); off += (size_t)MROWS * DIM * 2; // [b,h,s,d] bf16
  uint16_t* Kw = (uint16_t*)(ws + off); off += (size_t)MROWS * DIM * 2; // [b,h,s,d] bf16 swz
  uint16_t* Vw = (uint16_t*)(ws + off); off += (size_t)MROWS * DIM * 2; // [b,h,d,s] f16 swz
  uint16_t* AO = (uint16_t*)(ws + off); off += (size_t)MROWS * DIM * 2; // [m,768] bf16
  float* Out = (float*)d_out;

  int nx4 = MROWS * DIM / 4;
  cvt_bf16_kernel<<<2 * nx4 / 256, 256, 0, stream>>>(from_t, Xf, to_t, Xt, nx4);
  int nwords = BSZ * 32 * SEQ;
  mask_bits_kernel<<<nwords * 64 / 256, 256, 0, stream>>>(maski, Mbits, nwords);
  wtrans_kernel<<<dim3(24, 24, 4), dim3(32, 8), 0, stream>>>(Wq, Wk, Wv, Wo, WT);

  gemm_kernel<<<dim3(64, 6, 3), 256, 0, stream>>>(Xf, Xt, WT, AO, bq, bk, bv, bo,
                                                  Qw, Kw, Vw, Out, 0);
  flash_kernel<<<dim3(SEQ / 64, BSZ * NH), 256, 0, stream>>>(Qw, Kw, Vw, Mbits, AO);
  gemm_kernel<<<dim3(64, 6, 1), 256, 0, stream>>>(Xf, Xt, WT, AO, bq, bk, bv, bo,
                                                  Qw, Kw, Vw, Out, 3);
}

// Round 6
// 329.338 us; speedup vs baseline: 1.3688x; 1.0751x over previous
//
#include <hip/hip_runtime.h>
#include <stdint.h>

#define DIM 768
#define NH 12
#define HD 64
#define BSZ 4
#define SEQ 2048
#define MROWS (BSZ*SEQ)   // 8192

typedef __attribute__((ext_vector_type(8))) short v8s;        // 8 bf16 (4 VGPRs)
typedef __attribute__((ext_vector_type(4))) float v4f;        // 4 fp32 acc
typedef __attribute__((ext_vector_type(8))) _Float16 v8h;     // 8 f16 (4 VGPRs)
typedef __attribute__((ext_vector_type(2))) __fp16 v2fp;      // cvt_pkrtz native type

__device__ __forceinline__ uint16_t f2bf(float x) {
  union { float f; uint32_t u; } v; v.f = x;
  uint32_t r = v.u + 0x7fffu + ((v.u >> 16) & 1u);   // RNE
  return (uint16_t)(r >> 16);
}

#if __has_builtin(__builtin_amdgcn_cvt_pk_bf16_f32)
typedef __attribute__((ext_vector_type(2))) __bf16 v2bf;
__device__ __forceinline__ uint32_t pack_bf16(float a, float b) {
  union { v2bf v; uint32_t u; } c;
  c.v = __builtin_amdgcn_cvt_pk_bf16_f32(a, b);
  return c.u;
}
#else
__device__ __forceinline__ uint32_t pack_bf16(float a, float b) {
  return (uint32_t)f2bf(a) | ((uint32_t)f2bf(b) << 16);
}
#endif

__device__ __forceinline__ uint32_t pack_f16(float a, float b) {
#if __has_builtin(__builtin_amdgcn_cvt_pkrtz)
  union { v2fp h; uint32_t u; } c;
  c.h = __builtin_amdgcn_cvt_pkrtz(a, b);
  return c.u;
#else
  union { _Float16 h[2]; uint32_t u; } c;
  c.h[0] = (_Float16)a; c.h[1] = (_Float16)b; return c.u;
#endif
}

__device__ __forceinline__ float fexp2(float x) {
#if __has_builtin(__builtin_amdgcn_exp2f)
  return __builtin_amdgcn_exp2f(x);
#else
  return exp2f(x);
#endif
}

// async global->LDS, 16B per lane; LDS dst = wave-uniform base + lane*16
__device__ __forceinline__ void gl16(const void* g, void* l) {
  __builtin_amdgcn_global_load_lds(
      (const __attribute__((address_space(1))) unsigned int*)g,
      (__attribute__((address_space(3))) unsigned int*)l, 16, 0, 0);
}

// ---------------- pre-pass: fp32 -> bf16 (both X tensors, one launch) ----------
__global__ void cvt_bf16_kernel(const float* __restrict__ src0, uint16_t* __restrict__ dst0,
                                const float* __restrict__ src1, uint16_t* __restrict__ dst1,
                                int n4) {
  int i = blockIdx.x * blockDim.x + threadIdx.x;
  const float* src = (i < n4) ? src0 : src1;
  uint16_t* dst = (i < n4) ? dst0 : dst1;
  int j = (i < n4) ? i : i - n4;
  float4 v = ((const float4*)src)[j];
  ushort4 o;
  o.x = f2bf(v.x); o.y = f2bf(v.y); o.z = f2bf(v.z); o.w = f2bf(v.w);
  ((ushort4*)dst)[j] = o;
}

// ---------------- pre-pass: mask int32 -> u64 bitmask [b][kt][q] ----------------
__global__ void mask_bits_kernel(const int* __restrict__ src,
                                 unsigned long long* __restrict__ dst, int nwords) {
  int gtid = blockIdx.x * blockDim.x + threadIdx.x;
  int w = gtid >> 6;
  int lane = threadIdx.x & 63;
  if (w >= nwords) return;
  int b  = w >> 16;
  int q  = (w >> 5) & 2047;
  int kt = w & 31;
  int m = src[((size_t)b * SEQ + q) * SEQ + kt * 64 + lane];
  unsigned long long bits = __ballot(m != 0);
  if (lane == 0) dst[((size_t)b * 32 + kt) * SEQ + q] = bits;
}

// ---------------- pre-pass: W [K][N] fp32 -> WT [N][K] bf16 ----------------
__global__ void wtrans_kernel(const float* __restrict__ Wq, const float* __restrict__ Wk,
                              const float* __restrict__ Wv, const float* __restrict__ Wo,
                              uint16_t* __restrict__ WT) {
  __shared__ float tile[32][33];
  int z = blockIdx.z;
  const float* src = (z==0) ? Wq : (z==1) ? Wk : (z==2) ? Wv : Wo;
  uint16_t* dst = WT + (size_t)z * DIM * DIM;
  int tx = threadIdx.x, ty = threadIdx.y;
  int x  = blockIdx.x * 32 + tx;
  int y0 = blockIdx.y * 32;
  for (int j = ty; j < 32; j += 8)
    tile[j][tx] = src[(size_t)(y0 + j) * DIM + x];
  __syncthreads();
  int xo = y0 + tx;
  for (int j = ty; j < 32; j += 8)
    dst[(size_t)(blockIdx.x * 32 + j) * DIM + xo] = f2bf(tile[tx][j]);
}

// ---------------- GEMM (m97-style DMA staging): C = A(bf16) @ WT^T + bias ------
// LDS: 128 rows x 32 elems, lane-linear 16B chunks; source-side XOR swizzle
// seg = (lane&3)^((lane>>3)&3); frag chunk = quad^((lr>>1)&3) -> 2-way (free).
// mode 0: Q -> Qw [b,h,s,d]*(SCALE*log2e)  mode 1: K -> Kw (d-chunk swz by s&7)
// mode 2: V -> Vw [b,h,d,s] f16, kk pair-permuted + chunk swz by d&7
// mode 3: O -> d_out fp32 [m,n]
__global__ __launch_bounds__(256) void gemm_kernel(
    const uint16_t* __restrict__ Xf, const uint16_t* __restrict__ Xt,
    const uint16_t* __restrict__ WT, const uint16_t* __restrict__ AO,
    const float* __restrict__ bq, const float* __restrict__ bk,
    const float* __restrict__ bv, const float* __restrict__ bo,
    uint16_t* __restrict__ Qw, uint16_t* __restrict__ Kw, uint16_t* __restrict__ Vw,
    float* __restrict__ Out, int mode_base)
{
  __shared__ alignas(16) uint16_t As[128 * 32];
  __shared__ alignas(16) uint16_t Bs[128 * 32];
  int mode = mode_base + blockIdx.z;
  const uint16_t* A = (mode == 0) ? Xf : (mode == 3 ? AO : Xt);
  const uint16_t* W = WT + (size_t)mode * DIM * DIM;
  const float* bias = (mode == 0) ? bq : (mode == 1) ? bk : (mode == 2) ? bv : bo;

  int m0 = blockIdx.x * 128, n0 = blockIdx.y * 128;
  int tid = threadIdx.x;
  int wave = tid >> 6, lane = tid & 63, lr = lane & 15, quad = lane >> 4;
  int wm = (wave >> 1) * 64, wn = (wave & 1) * 64;

  int seg = (lane & 3) ^ ((lane >> 3) & 3);
  const uint16_t* agl = A + (size_t)(m0 + wave * 32 + (lane >> 2)) * DIM + seg * 8;
  const uint16_t* bgl = W + (size_t)(n0 + wave * 32 + (lane >> 2)) * DIM + seg * 8;
  int lb = wave * 1024;             // uint16 idx; call c adds 512
  int ck = (lr >> 1) & 3;

  v4f acc[4][4];
  v4f vz = {0.f, 0.f, 0.f, 0.f};
  #pragma unroll
  for (int i = 0; i < 4; i++)
    #pragma unroll
    for (int j = 0; j < 4; j++) acc[i][j] = vz;

  for (int k0 = 0; k0 < DIM; k0 += 32) {
    __syncthreads();
    gl16(agl + k0,            &As[lb]);
    gl16(agl + k0 + 16 * DIM, &As[lb + 512]);
    gl16(bgl + k0,            &Bs[lb]);
    gl16(bgl + k0 + 16 * DIM, &Bs[lb + 512]);
    __syncthreads();
    v8s af[4], bfr[4];
    #pragma unroll
    for (int i = 0; i < 4; i++)
      af[i] = *(const v8s*)&As[(wm + i * 16 + lr) * 32 + ((quad ^ ck) << 3)];
    #pragma unroll
    for (int j = 0; j < 4; j++)
      bfr[j] = *(const v8s*)&Bs[(wn + j * 16 + lr) * 32 + ((quad ^ ck) << 3)];
    #pragma unroll
    for (int i = 0; i < 4; i++)
      #pragma unroll
      for (int j = 0; j < 4; j++)
        acc[i][j] = __builtin_amdgcn_mfma_f32_16x16x32_bf16(af[i], bfr[j], acc[i][j], 0, 0, 0);
  }

  float bj[4];
  #pragma unroll
  for (int j = 0; j < 4; j++) bj[j] = bias[n0 + wn + j * 16 + lr];

  if (mode == 3) {
    #pragma unroll
    for (int i = 0; i < 4; i++) {
      int m = m0 + wm + i * 16 + quad * 4;
      #pragma unroll
      for (int j = 0; j < 4; j++) {
        int n = n0 + wn + j * 16 + lr;
        #pragma unroll
        for (int r = 0; r < 4; r++)
          Out[(size_t)(m + r) * DIM + n] = acc[i][j][r] + bj[j];
      }
    }
  } else if (mode == 2) {
    // Vw f16 [b,h,d,s]: within each 64-kk group, pos = pair*32+quadk*8+(nt&1)*4+j,
    // then 16B-chunk XOR-swizzled by d&7.  (kk = s&63; pair=kk>>5, nt=(kk>>4)&1,
    // quadk=(kk>>2)&3, j=kk&3 — j==r here since s0 is 4-aligned.)
    #pragma unroll
    for (int i = 0; i < 4; i++) {
      int m = m0 + wm + i * 16 + quad * 4;
      int b = m >> 11, s0 = m & 2047;
      int kk0 = s0 & 63;
      int pos = (kk0 >> 5) * 32 + ((kk0 >> 2) & 3) * 8 + ((kk0 >> 4) & 1) * 4;
      int chunk = pos >> 3, off = pos & 7;
      #pragma unroll
      for (int j = 0; j < 4; j++) {
        int n = n0 + wn + j * 16 + lr;
        int h = n >> 6, d = n & 63;
        uint2 pk;
        pk.x = pack_f16(acc[i][j][0] + bj[j], acc[i][j][1] + bj[j]);
        pk.y = pack_f16(acc[i][j][2] + bj[j], acc[i][j][3] + bj[j]);
        int idx = (s0 & ~63) + ((chunk ^ (d & 7)) << 3) + off;
        *(uint2*)&Vw[((size_t)(b * NH + h) * HD + d) * SEQ + idx] = pk;
      }
    }
  } else {
    uint16_t* Dst = (mode == 0) ? Qw : Kw;
    float scale = (mode == 0) ? 0.18033688f : 1.0f;   // HD^-0.5 * log2(e) folded into Q
    #pragma unroll
    for (int i = 0; i < 4; i++) {
      int m = m0 + wm + i * 16 + quad * 4;
      int b = m >> 11, s0 = m & 2047;
      #pragma unroll
      for (int j = 0; j < 4; j++) {
        int n = n0 + wn + j * 16 + lr;
        int h = n >> 6, d = n & 63;
        #pragma unroll
        for (int r = 0; r < 4; r++) {
          float v = (acc[i][j][r] + bj[j]) * scale;
          int s = s0 + r;
          int dd = (mode == 1) ? ((((d >> 3) ^ (s & 7)) << 3) + (d & 7)) : d;
          Dst[((size_t)(b * NH + h) * SEQ + s) * HD + dd] = f2bf(v);
        }
      }
    }
  }
}

// ---------------- flash attention: 32 q/wave, x32-f16 PV with permuted kk -------
// S^T = K.Q^T per q-group g (C-layout: lane lr owns q, kk=nt*16+quad*4+r).
// PV uses mfma_f32_16x16x32_f16 with a permuted contraction order: the v8h built
// from (nt=2p, nt=2p+1) sacc registers IS the B-frag, and Vw's baked layout makes
// one ds_read_b128 the matching A-frag.  p = 2^(s-8) (f16-range bias, cancels).
__device__ __forceinline__ void softmax8(unsigned long long mw, int sh0,
                                         const v4f* s, v8h* pf, float& lsum) {
  uint32_t mlo = (uint32_t)mw, mhi = (uint32_t)(mw >> 32);
  #pragma unroll
  for (int p = 0; p < 2; p++) {
    float ps[8];
    #pragma unroll
    for (int half = 0; half < 2; half++) {
      int nt = p * 2 + half;
      uint32_t b4 = ((nt < 2 ? mlo : mhi) >> (sh0 + ((nt & 1) << 4))) & 15u;
      #pragma unroll
      for (int r = 0; r < 4; r++) {
        float v = fexp2(s[nt][r] - 8.0f) * (float)((b4 >> r) & 1u);
        ps[half * 4 + r] = v;
        lsum += v;
      }
    }
    union { uint4 u; v8h h; } cc;
    cc.u.x = pack_f16(ps[0], ps[1]);
    cc.u.y = pack_f16(ps[2], ps[3]);
    cc.u.z = pack_f16(ps[4], ps[5]);
    cc.u.w = pack_f16(ps[6], ps[7]);
    pf[p] = cc.h;
  }
}

__global__ __launch_bounds__(128, 3) void flash_kernel(
    const uint16_t* __restrict__ Qg, const uint16_t* __restrict__ Kg,
    const uint16_t* __restrict__ Vg, const unsigned long long* __restrict__ Mb,
    uint16_t* __restrict__ AO)
{
  __shared__ alignas(16) uint16_t Ks[64 * 64];   // 8 KB, swizzle baked in global Kw
  __shared__ alignas(16) uint16_t Vs[64 * 64];   // 8 KB f16, perm+swizzle baked in Vw

  int tid = threadIdx.x, wave = tid >> 6, lane = tid & 63, lr = lane & 15, quad = lane >> 4;
  int bh = blockIdx.y;
  int b = bh / NH, h = bh - b * NH;
  int q0 = blockIdx.x * 64;
  const uint16_t* Qp = Qg + (size_t)bh * SEQ * HD;
  const uint16_t* Kp = Kg + (size_t)bh * SEQ * HD;
  const uint16_t* Vp = Vg + (size_t)bh * HD * SEQ;
  int qg0 = q0 + wave * 32 + lr;
  int qg1 = qg0 + 16;
  const unsigned long long* Mp0 = Mb + (size_t)b * 32 * SEQ + qg0;
  const unsigned long long* Mp1 = Mp0 + 16;

  int swk = lr & 7, sh0 = quad * 4;

  v8s qf0a = *(const v8s*)&Qp[(size_t)qg0 * HD + quad * 8];
  v8s qf0b = *(const v8s*)&Qp[(size_t)qg0 * HD + 32 + quad * 8];
  v8s qf1a = *(const v8s*)&Qp[(size_t)qg1 * HD + quad * 8];
  v8s qf1b = *(const v8s*)&Qp[(size_t)qg1 * HD + 32 + quad * 8];

  // DMA: 2 waves x 4 calls x 64 lanes x 16B = 8 KB per buffer
  const uint16_t* kgl = Kp + ((size_t)(wave * 32 + (lane >> 3)) * HD + (lane & 7) * 8);
  const uint16_t* vgl = Vp + ((size_t)(wave * 32 + (lane >> 3)) * SEQ + (lane & 7) * 8);
  int lb = wave * 2048;   // uint16 idx; call c adds 512

  v4f acc0[4], acc1[4];
  v4f vz = {0.f, 0.f, 0.f, 0.f};
  #pragma unroll
  for (int dt = 0; dt < 4; dt++) { acc0[dt] = vz; acc1[dt] = vz; }
  float ls0 = 0.f, ls1 = 0.f;

  for (int k0 = 0; k0 < SEQ; k0 += 64) {
    __syncthreads();                               // prev tile's LDS reads done
    #pragma unroll
    for (int c = 0; c < 4; c++) {
      gl16(kgl + ((size_t)k0 + c * 8) * HD, &Ks[lb + c * 512]);
      gl16(vgl + k0 + (size_t)c * 8 * SEQ, &Vs[lb + c * 512]);
    }
    unsigned long long mw0 = Mp0[(size_t)(k0 >> 6) * SEQ];
    unsigned long long mw1 = Mp1[(size_t)(k0 >> 6) * SEQ];
    __syncthreads();                               // DMA complete

    // S^T = K.Q^T for both q-groups (K A-frags shared)
    v4f s0[4], s1[4];
    #pragma unroll
    for (int nt = 0; nt < 4; nt++) {
      int rowb = (nt * 16 + lr) << 6;
      v8s kf0 = *(const v8s*)&Ks[rowb + ((quad ^ swk) << 3)];
      v8s kf1 = *(const v8s*)&Ks[rowb + (((quad + 4) ^ swk) << 3)];
      v4f z = vz;
      z = __builtin_amdgcn_mfma_f32_16x16x32_bf16(kf0, qf0a, z, 0, 0, 0);
      z = __builtin_amdgcn_mfma_f32_16x16x32_bf16(kf1, qf0b, z, 0, 0, 0);
      s0[nt] = z;
      z = vz;
      z = __builtin_amdgcn_mfma_f32_16x16x32_bf16(kf0, qf1a, z, 0, 0, 0);
      z = __builtin_amdgcn_mfma_f32_16x16x32_bf16(kf1, qf1b, z, 0, 0, 0);
      s1[nt] = z;
    }

    v8h pf0[2], pf1[2];
    softmax8(mw0, sh0, s0, pf0, ls0);
    softmax8(mw1, sh0, s1, pf1, ls1);

    // O^T += V^T.P^T : one b128 A-frag per (dt, pair), shared across q-groups
    #pragma unroll
    for (int dt = 0; dt < 4; dt++) {
      int rowb = (dt * 16 + lr) << 6;
      #pragma unroll
      for (int p = 0; p < 2; p++) {
        v8h vv = *(const v8h*)&Vs[rowb + (((p * 4 + quad) ^ swk) << 3)];
        acc0[dt] = __builtin_amdgcn_mfma_f32_16x16x32_f16(vv, pf0[p], acc0[dt], 0, 0, 0);
        acc1[dt] = __builtin_amdgcn_mfma_f32_16x16x32_f16(vv, pf1[p], acc1[dt], 0, 0, 0);
      }
    }
  }

  ls0 += __shfl_xor(ls0, 16); ls0 += __shfl_xor(ls0, 32);
  ls1 += __shfl_xor(ls1, 16); ls1 += __shfl_xor(ls1, 32);
  float ri0 = 1.0f / ls0, ri1 = 1.0f / ls1;

  #pragma unroll
  for (int dt = 0; dt < 4; dt++) {
    uint2 pk;
    pk.x = pack_bf16(acc0[dt][0] * ri0, acc0[dt][1] * ri0);
    pk.y = pack_bf16(acc0[dt][2] * ri0, acc0[dt][3] * ri0);
    *(uint2*)&AO[(size_t)(b * SEQ + qg0) * DIM + h * HD + dt * 16 + sh0] = pk;
    pk.x = pack_bf16(acc1[dt][0] * ri1, acc1[dt][1] * ri1);
    pk.y = pack_bf16(acc1[dt][2] * ri1, acc1[dt][3] * ri1);
    *(uint2*)&AO[(size_t)(b * SEQ + qg1) * DIM + h * HD + dt * 16 + sh0] = pk;
  }
}

// ---------------- launch ----------------
extern "C" void kernel_launch(void* const* d_in, const int* in_sizes, int n_in,
                              void* d_out, int out_size, void* d_ws, size_t ws_size,
                              hipStream_t stream) {
  const float* from_t = (const float*)d_in[0];
  const float* to_t   = (const float*)d_in[1];
  const int*   maski  = (const int*)d_in[2];
  const float* Wq = (const float*)d_in[3];  const float* bq = (const float*)d_in[4];
  const float* Wk = (const float*)d_in[5];  const float* bk = (const float*)d_in[6];
  const float* Wv = (const float*)d_in[7];  const float* bv = (const float*)d_in[8];
  const float* Wo = (const float*)d_in[9];  const float* bo = (const float*)d_in[10];

  char* ws = (char*)d_ws;
  size_t off = 0;
  uint16_t* Xf = (uint16_t*)(ws + off); off += (size_t)MROWS * DIM * 2;
  uint16_t* Xt = (uint16_t*)(ws + off); off += (size_t)MROWS * DIM * 2;
  uint16_t* WT = (uint16_t*)(ws + off); off += (size_t)4 * DIM * DIM * 2;
  unsigned long long* Mbits = (unsigned long long*)(ws + off);
  off += (size_t)BSZ * 32 * SEQ * 8;                                    // 2 MB
  uint16_t* Qw = (uint16_t*)(ws + off); off += (size_t)MROWS * DIM * 2; // [b,h,s,d] bf16
  uint16_t* Kw = (uint16_t*)(ws + off); off += (size_t)MROWS * DIM * 2; // [b,h,s,d] bf16 swz
  uint16_t* Vw = (uint16_t*)(ws + off); off += (size_t)MROWS * DIM * 2; // [b,h,d,s] f16 perm+swz
  uint16_t* AO = (uint16_t*)(ws + off); off += (size_t)MROWS * DIM * 2; // [m,768] bf16
  float* Out = (float*)d_out;

  int nx4 = MROWS * DIM / 4;
  cvt_bf16_kernel<<<2 * nx4 / 256, 256, 0, stream>>>(from_t, Xf, to_t, Xt, nx4);
  int nwords = BSZ * 32 * SEQ;
  mask_bits_kernel<<<nwords * 64 / 256, 256, 0, stream>>>(maski, Mbits, nwords);
  wtrans_kernel<<<dim3(24, 24, 4), dim3(32, 8), 0, stream>>>(Wq, Wk, Wv, Wo, WT);

  gemm_kernel<<<dim3(64, 6, 3), 256, 0, stream>>>(Xf, Xt, WT, AO, bq, bk, bv, bo,
                                                  Qw, Kw, Vw, Out, 0);
  flash_kernel<<<dim3(SEQ / 64, BSZ * NH), 128, 0, stream>>>(Qw, Kw, Vw, Mbits, AO);
  gemm_kernel<<<dim3(64, 6, 1), 256, 0, stream>>>(Xf, Xt, WT, AO, bq, bk, bv, bo,
                                                  Qw, Kw, Vw, Out, 3);
}